// Round 12
// baseline (10997.106 us; speedup 1.0000x reference)
//
#include <hip/hip_runtime.h>
#include <hip/hip_bf16.h>

using bf16 = __hip_bfloat16;

#define N_B 200000
#define E_B 3200000
#define N_P 100000
#define E_P 1600000

__device__ __forceinline__ bf16  w12_f2b(float v) { return __float2bfloat16(v); }
__device__ __forceinline__ float w12_b2f(bf16 v)  { return __bfloat162float(v); }

// ---------------------------------------------------------------------------
// Fused 2-layer MLP, one node per block (proven structure).
// ---------------------------------------------------------------------------
template <int K1, int K2, int H, int OUT, int BLOCK>
__global__ __launch_bounds__(BLOCK) void w12_mlp2(
    const float* __restrict__ x1, int s1,
    const float* __restrict__ x2, int s2,
    const float* __restrict__ w1, const float* __restrict__ b1, const float* __restrict__ a1p,
    const float* __restrict__ w2, const float* __restrict__ b2, const float* __restrict__ a2p,
    float* __restrict__ out, int out_stride)
{
    constexpr int K = K1 + K2;
    __shared__ float xs[K];
    __shared__ float hs[H];

    const int n   = blockIdx.x;
    const int tid = threadIdx.x;

    for (int k = tid; k < K; k += BLOCK)
        xs[k] = (k < K1) ? x1[(size_t)n * s1 + k]
                         : x2[(size_t)n * s2 + (k - K1)];
    __syncthreads();

    const float a1 = a1p[0];
    const float a2 = a2p[0];

    for (int h = tid; h < H; h += BLOCK) {
        float acc = b1[h];
        for (int k = 0; k < K; ++k) acc += xs[k] * w1[(size_t)k * H + h];
        hs[h] = acc > 0.f ? acc : a1 * acc;
    }
    __syncthreads();

    for (int o = tid; o < OUT; o += BLOCK) {
        float acc = b2[o];
        for (int h = 0; h < H; ++h) acc += hs[h] * w2[(size_t)h * OUT + o];
        acc = acc > 0.f ? acc : a2 * acc;
        out[(size_t)n * out_stride + o] = acc;
    }
}

// ---------------------------------------------------------------------------
// Y[N][OUT] (bf16) = X[N][K] (f32) @ W[K][OUT] (f32)
// ---------------------------------------------------------------------------
template <int K, int OUT>
__global__ __launch_bounds__(256) void w12_gemm(
    const float* __restrict__ X, const float* __restrict__ W,
    bf16* __restrict__ Y, int N)
{
    int idx = blockIdx.x * 256 + threadIdx.x;
    if (idx >= N * OUT) return;
    int n = idx / OUT, o = idx % OUT;
    const float* xr = X + (size_t)n * K;
    float acc = 0.f;
#pragma unroll 8
    for (int k = 0; k < K; ++k) acc += xr[k] * W[(size_t)k * OUT + o];
    Y[idx] = w12_f2b(acc);
}

// ---------------------------------------------------------------------------
// CSR build (int atomics only; proven)
// ---------------------------------------------------------------------------
__global__ __launch_bounds__(256) void w12_zero_int(int* __restrict__ p, int n)
{
    int i = blockIdx.x * 256 + threadIdx.x;
    if (i < n) p[i] = 0;
}

__global__ __launch_bounds__(256) void w12_hist(
    const int* __restrict__ dst, int* __restrict__ rowp, int E)
{
    int i = blockIdx.x * 256 + threadIdx.x;
    if (i < E) atomicAdd(&rowp[dst[i] + 1], 1);
}

__global__ __launch_bounds__(256) void w12_scan(int* __restrict__ data, int n)
{
    __shared__ int buf[256];
    __shared__ int carry;
    if (threadIdx.x == 0) carry = 0;
    __syncthreads();
    for (int base = 0; base < n; base += 256) {
        int i = base + threadIdx.x;
        int v = (i < n) ? data[i] : 0;
        buf[threadIdx.x] = v;
        __syncthreads();
        for (int off = 1; off < 256; off <<= 1) {
            int t = (threadIdx.x >= off) ? buf[threadIdx.x - off] : 0;
            __syncthreads();
            buf[threadIdx.x] += t;
            __syncthreads();
        }
        int c = carry;
        if (i < n) data[i] = buf[threadIdx.x] + c;
        __syncthreads();
        if (threadIdx.x == 255) carry = c + buf[255];
        __syncthreads();
    }
}

__global__ __launch_bounds__(256) void w12_copy_int(
    const int* __restrict__ src, int* __restrict__ dstp, int n)
{
    int i = blockIdx.x * 256 + threadIdx.x;
    if (i < n) dstp[i] = src[i];
}

__global__ __launch_bounds__(256) void w12_fill(
    const int* __restrict__ src, const int* __restrict__ dst,
    int* __restrict__ curs, int* __restrict__ col, int E)
{
    int i = blockIdx.x * 256 + threadIdx.x;
    if (i >= E) return;
    int pos = atomicAdd(&curs[dst[i]], 1);
    col[pos] = src[i];
}

__global__ __launch_bounds__(256) void w12_dis(
    const int* __restrict__ rowp, float* __restrict__ dis, int n)
{
    int i = blockIdx.x * 256 + threadIdx.x;
    if (i < n) dis[i] = 1.0f / sqrtf((float)(rowp[i + 1] - rowp[i] + 1));
}

// ---------------------------------------------------------------------------
// Fused GCN aggregation (gather); f32 output; optional f32 mirror to d_out.
// ---------------------------------------------------------------------------
template <int W, bool RELU, bool FOUT>
__global__ __launch_bounds__(256) void w12_gcn(
    const int* __restrict__ rowp, const int* __restrict__ col,
    const float* __restrict__ dis, const bf16* __restrict__ h,
    const float* __restrict__ bias, float* __restrict__ out,
    float* __restrict__ fout, int N)
{
    int t = blockIdx.x * 256 + threadIdx.x;
    int n = t / W, j = t % W;
    if (n >= N) return;
    const float dn  = dis[n];
    const int   beg = rowp[n], end = rowp[n + 1];
    float acc = 0.f;
    for (int e = beg; e < end; ++e) {
        int s = col[e];
        acc += dis[s] * w12_b2f(h[(size_t)s * W + j]);
    }
    float v = dn * acc + dn * dn * w12_b2f(h[(size_t)n * W + j]) + bias[j];
    if (RELU) v = fmaxf(v, 0.f);
    out[(size_t)n * W + j] = v;
    if (FOUT) fout[(size_t)n * W + j] = v;   // FLOAT32 output
}

// ---------------------------------------------------------------------------
// decode: sigmoid(dot32(z[src], z[dst])); 32 lanes per edge; FLOAT32 output
// ---------------------------------------------------------------------------
__global__ __launch_bounds__(256) void w12_decode(
    const int* __restrict__ src, const int* __restrict__ dst,
    const float* __restrict__ z, float* __restrict__ out, int E)
{
    int t = blockIdx.x * 256 + threadIdx.x;
    int e = t >> 5, j = t & 31;
    if (e >= E) return;
    float v = z[(size_t)src[e] * 32 + j] * z[(size_t)dst[e] * 32 + j];
#pragma unroll
    for (int off = 16; off > 0; off >>= 1) v += __shfl_down(v, off, 32);
    if (j == 0) out[e] = 1.f / (1.f + expf(-v));
}

// ---------------------------------------------------------------------------
extern "C" void kernel_launch(void* const* d_in, const int* in_sizes, int n_in,
                              void* d_out, int out_size, void* d_ws, size_t ws_size,
                              hipStream_t stream)
{
    const float* bcat  = (const float*)d_in[0];
    const float* bdesc = (const float*)d_in[1];
    const float* pcat  = (const float*)d_in[2];
    const int*   eib   = (const int*)d_in[3];
    const int*   eip   = (const int*)d_in[4];

    const float *bc_w1=(const float*)d_in[5],  *bc_b1=(const float*)d_in[6],  *bc_a1=(const float*)d_in[7];
    const float *bc_w2=(const float*)d_in[8],  *bc_b2=(const float*)d_in[9],  *bc_a2=(const float*)d_in[10];
    const float *bd_w1=(const float*)d_in[11], *bd_b1=(const float*)d_in[12], *bd_a1=(const float*)d_in[13];
    const float *bd_w2=(const float*)d_in[14], *bd_b2=(const float*)d_in[15], *bd_a2=(const float*)d_in[16];
    const float *bf_w1=(const float*)d_in[17], *bf_b1=(const float*)d_in[18], *bf_a1=(const float*)d_in[19];
    const float *bf_w2=(const float*)d_in[20], *bf_b2=(const float*)d_in[21], *bf_a2=(const float*)d_in[22];
    const float *pc_w1=(const float*)d_in[23], *pc_b1=(const float*)d_in[24], *pc_a1=(const float*)d_in[25];
    const float *pc_w2=(const float*)d_in[26], *pc_b2=(const float*)d_in[27], *pc_a2=(const float*)d_in[28];
    const float *gb_w1=(const float*)d_in[29], *gb_b1=(const float*)d_in[30];
    const float *gb_w2=(const float*)d_in[31], *gb_b2=(const float*)d_in[32];
    const float *gp_w1=(const float*)d_in[33], *gp_b1=(const float*)d_in[34];
    const float *gp_w2=(const float*)d_in[35], *gp_b2=(const float*)d_in[36];

    const int* srcB = eib;  const int* dstB = eib + E_B;
    const int* srcP = eip;  const int* dstP = eip + E_P;

    // proven 92 MB ws layout
    int*   rowp = (int*)d_ws;               // 200001
    int*   curs = rowp + 200001;            // 200000
    int*   col  = curs + 200000;            // 3200000
    float* dis  = (float*)(col + 3200000);  // 200000
    float* A    = dis + 200000;             // 12800000 f32
    bf16*  Bh   = (bf16*)(A + 12800000);    // 12800000 bf16 (6.4M words)
    float* BhF  = (float*)Bh;
    float* A2   = A + 6400000;

    // FLOAT32 outputs (reference output dtype is float32)
    float* out_zb = (float*)d_out;          // [N_B x 32] = 6,400,000
    float* out_ab = out_zb + 6400000;       // [E_B]      = 3,200,000
    float* out_zp = out_ab + 3200000;       // [N_P x 32] = 3,200,000
    float* out_ap = out_zp + 3200000;       // [E_P]      = 1,600,000

    // ================= buildings: CSR =======================================
    w12_zero_int<<<(N_B + 1 + 255) / 256, 256, 0, stream>>>(rowp, N_B + 1);
    w12_hist    <<<(E_B + 255) / 256, 256, 0, stream>>>(dstB, rowp, E_B);
    w12_scan    <<<1, 256, 0, stream>>>(rowp, N_B + 1);
    w12_copy_int<<<(N_B + 255) / 256, 256, 0, stream>>>(rowp, curs, N_B);
    w12_fill    <<<(E_B + 255) / 256, 256, 0, stream>>>(srcB, dstB, curs, col, E_B);
    w12_dis     <<<(N_B + 255) / 256, 256, 0, stream>>>(rowp, dis, N_B);

    // ================= buildings: MLPs ======================================
    w12_mlp2<110,0,512,64,512><<<N_B,512,0,stream>>>(
        bcat,110, (const float*)nullptr,0,
        bc_w1,bc_b1,bc_a1, bc_w2,bc_b2,bc_a2, A,64);
    w12_mlp2<13,0,64,32,128><<<N_B,128,0,stream>>>(
        bdesc,13, (const float*)nullptr,0,
        bd_w1,bd_b1,bd_a1, bd_w2,bd_b2,bd_a2, BhF,32);
    w12_mlp2<64,32,512,64,512><<<N_B,512,0,stream>>>(
        A,64, BhF,32,
        bf_w1,bf_b1,bf_a1, bf_w2,bf_b2,bf_a2, A,64);

    // ================= buildings: GCN + decode ==============================
    w12_gemm<64,64><<<(N_B*64 + 255)/256, 256, 0, stream>>>(A, gb_w1, Bh, N_B);
    w12_gcn<64,true,false><<<(N_B*64 + 255)/256, 256, 0, stream>>>(
        rowp, col, dis, Bh, gb_b1, A, (float*)nullptr, N_B);
    w12_gemm<64,32><<<(N_B*32 + 255)/256, 256, 0, stream>>>(A, gb_w2, Bh, N_B);
    w12_gcn<32,false,true><<<(N_B*32 + 255)/256, 256, 0, stream>>>(
        rowp, col, dis, Bh, gb_b2, A, out_zb, N_B);

    w12_decode<<<(E_B*32 + 255)/256, 256, 0, stream>>>(srcB, dstB, A, out_ab, E_B);

    // ================= POIs =================================================
    w12_zero_int<<<(N_P + 1 + 255) / 256, 256, 0, stream>>>(rowp, N_P + 1);
    w12_hist    <<<(E_P + 255) / 256, 256, 0, stream>>>(dstP, rowp, E_P);
    w12_scan    <<<1, 256, 0, stream>>>(rowp, N_P + 1);
    w12_copy_int<<<(N_P + 255) / 256, 256, 0, stream>>>(rowp, curs, N_P);
    w12_fill    <<<(E_P + 255) / 256, 256, 0, stream>>>(srcP, dstP, curs, col, E_P);
    w12_dis     <<<(N_P + 255) / 256, 256, 0, stream>>>(rowp, dis, N_P);

    w12_mlp2<401,0,512,64,512><<<N_P,512,0,stream>>>(
        pcat,401, (const float*)nullptr,0,
        pc_w1,pc_b1,pc_a1, pc_w2,pc_b2,pc_a2, A2,64);

    w12_gemm<64,64><<<(N_P*64 + 255)/256, 256, 0, stream>>>(A2, gp_w1, Bh, N_P);
    w12_gcn<64,true,false><<<(N_P*64 + 255)/256, 256, 0, stream>>>(
        rowp, col, dis, Bh, gp_b1, A2, (float*)nullptr, N_P);
    w12_gemm<64,32><<<(N_P*32 + 255)/256, 256, 0, stream>>>(A2, gp_w2, Bh, N_P);
    w12_gcn<32,false,true><<<(N_P*32 + 255)/256, 256, 0, stream>>>(
        rowp, col, dis, Bh, gp_b2, A2, out_zp, N_P);

    w12_decode<<<(E_P*32 + 255)/256, 256, 0, stream>>>(srcP, dstP, A2, out_ap, E_P);
}

// Round 13
// 4108.479 us; speedup vs baseline: 2.6767x; 2.6767x over previous
//
#include <hip/hip_runtime.h>
#include <hip/hip_bf16.h>

using bf16 = __hip_bfloat16;
typedef __attribute__((ext_vector_type(8))) short bf16x8_t;
typedef __attribute__((ext_vector_type(4))) float f32x4_t;

#define N_B 200000
#define E_B 3200000
#define N_P 100000
#define E_P 1600000

__device__ __forceinline__ bf16  w12_f2b(float v) { return __float2bfloat16(v); }
__device__ __forceinline__ float w12_b2f(bf16 v)  { return __bfloat162float(v); }

// f32 -> bf16 bit pattern, round-to-nearest-even
__device__ __forceinline__ unsigned short f2bits(float f)
{
    union { float f; unsigned u; } v; v.f = f;
    unsigned u = v.u;
    unsigned r = (u + 0x7FFFu + ((u >> 16) & 1u)) >> 16;
    return (unsigned short)r;
}

// ---------------------------------------------------------------------------
// Weight converter: w [K][H] f32 -> fragment-swizzled bf16
// dst[((kt*(H/16)+nt)*64 + lane)*8 + j] = bf16(w[kt*32 + (lane>>4)*8 + j][nt*16 + (lane&15)])
// (zero-padded for k >= K). ktiles = Kpad/32.
// ---------------------------------------------------------------------------
__global__ __launch_bounds__(256) void cvt_w(
    const float* __restrict__ w, unsigned short* __restrict__ dst,
    int K, int ktiles, int H)
{
    int total = ktiles * (H / 16) * 64;
    int idx = blockIdx.x * 256 + threadIdx.x;
    if (idx >= total) return;
    int lane = idx & 63;
    int t    = idx >> 6;          // kt*(H/16) + nt
    int nt   = t % (H / 16);
    int kt   = t / (H / 16);
    int kg   = lane >> 4, cl = lane & 15;
#pragma unroll
    for (int j = 0; j < 8; ++j) {
        int k = kt * 32 + kg * 8 + j;
        float v = (k < K) ? w[(size_t)k * H + nt * 16 + cl] : 0.f;
        dst[(size_t)idx * 8 + j] = f2bits(v);
    }
}

// ---------------------------------------------------------------------------
// MFMA fused 2-layer MLP: out = PReLU(PReLU(x@w1+b1,a1)@w2+b2,a2)
// 32 nodes/block, 256 threads (4 waves). x = concat(x1[K1], x2[K2]), KP padded.
// w1s/w2s are fragment-swizzled bf16. f32 accumulation. N % 32 == 0.
// Wave wv: m = wv&1 (16-node half), wg = wv>>1 (column half).
// ---------------------------------------------------------------------------
template <int K1, int K2, int KP, int H, int OUT>
__global__ __launch_bounds__(256) void mfma_mlp(
    const float* __restrict__ x1, int s1,
    const float* __restrict__ x2, int s2,
    const unsigned short* __restrict__ w1s, const float* __restrict__ b1, const float* __restrict__ a1p,
    const unsigned short* __restrict__ w2s, const float* __restrict__ b2, const float* __restrict__ a2p,
    float* __restrict__ out)
{
    constexpr int PAD = 8;
    constexpr int XS  = KP + PAD;    // xs row stride (bf16 elems)
    constexpr int HS  = H + PAD;     // hs row stride
    constexpr int NT1 = H / 16;      // layer-1 N tiles
    constexpr int TP1 = NT1 / 2;     // tiles per wave (2 wave-groups)
    constexpr int NT2 = OUT / 16;
    constexpr int TP2 = NT2 / 2;

    __shared__ unsigned short xs[32 * XS];
    __shared__ unsigned short hs[32 * HS];

    const int tid = threadIdx.x;
    const int n0  = blockIdx.x * 32;

    // stage x -> LDS bf16 (zero-pad K1+K2..KP)
    for (int i = tid; i < 32 * KP; i += 256) {
        int n = i / KP, k = i - n * KP;
        float v = 0.f;
        if (k < K1)            v = x1[(size_t)(n0 + n) * s1 + k];
        else if (k < K1 + K2)  v = x2[(size_t)(n0 + n) * s2 + (k - K1)];
        xs[n * XS + k] = f2bits(v);
    }
    __syncthreads();

    const float a1 = a1p[0], a2 = a2p[0];
    const int wv = tid >> 6, lane = tid & 63;
    const int m = wv & 1, wg = wv >> 1;
    const int kg = lane >> 4, cl = lane & 15;

    // ---------------- layer 1 ----------------
    const int ntb = wg * TP1;
    f32x4_t acc[TP1];
    const f32x4_t zero = {0.f, 0.f, 0.f, 0.f};
#pragma unroll
    for (int i = 0; i < TP1; ++i) acc[i] = zero;

    for (int kt = 0; kt < KP / 32; ++kt) {
        bf16x8_t a = *(const bf16x8_t*)(xs + (m * 16 + cl) * XS + kt * 32 + kg * 8);
#pragma unroll
        for (int i = 0; i < TP1; ++i) {
            bf16x8_t b = *(const bf16x8_t*)(w1s + ((size_t)(kt * NT1 + ntb + i) * 64 + lane) * 8);
            acc[i] = __builtin_amdgcn_mfma_f32_16x16x32_bf16(a, b, acc[i], 0, 0, 0);
        }
    }
#pragma unroll
    for (int i = 0; i < TP1; ++i) {
        int c = (ntb + i) * 16 + cl;
        float bb = b1[c];
#pragma unroll
        for (int r = 0; r < 4; ++r) {
            float v = acc[i][r] + bb;
            v = v > 0.f ? v : a1 * v;
            hs[(m * 16 + kg * 4 + r) * HS + c] = f2bits(v);
        }
    }
    __syncthreads();

    // ---------------- layer 2 ----------------
    const int ntb2 = wg * TP2;
    f32x4_t acc2[TP2];
#pragma unroll
    for (int i = 0; i < TP2; ++i) acc2[i] = zero;

    for (int kt = 0; kt < H / 32; ++kt) {
        bf16x8_t a = *(const bf16x8_t*)(hs + (m * 16 + cl) * HS + kt * 32 + kg * 8);
#pragma unroll
        for (int i = 0; i < TP2; ++i) {
            bf16x8_t b = *(const bf16x8_t*)(w2s + ((size_t)(kt * NT2 + ntb2 + i) * 64 + lane) * 8);
            acc2[i] = __builtin_amdgcn_mfma_f32_16x16x32_bf16(a, b, acc2[i], 0, 0, 0);
        }
    }
#pragma unroll
    for (int i = 0; i < TP2; ++i) {
        int c = (ntb2 + i) * 16 + cl;
        float bb = b2[c];
#pragma unroll
        for (int r = 0; r < 4; ++r) {
            float v = acc2[i][r] + bb;
            v = v > 0.f ? v : a2 * v;
            out[(size_t)(n0 + m * 16 + kg * 4 + r) * OUT + c] = v;
        }
    }
}

// ---------------------------------------------------------------------------
// Naive fused 2-layer MLP (kept for the tiny bd net 13->64->32)
// ---------------------------------------------------------------------------
template <int K1, int K2, int H, int OUT, int BLOCK>
__global__ __launch_bounds__(BLOCK) void w12_mlp2(
    const float* __restrict__ x1, int s1,
    const float* __restrict__ x2, int s2,
    const float* __restrict__ w1, const float* __restrict__ b1, const float* __restrict__ a1p,
    const float* __restrict__ w2, const float* __restrict__ b2, const float* __restrict__ a2p,
    float* __restrict__ out, int out_stride)
{
    constexpr int K = K1 + K2;
    __shared__ float xsm[K];
    __shared__ float hsm[H];

    const int n   = blockIdx.x;
    const int tid = threadIdx.x;

    for (int k = tid; k < K; k += BLOCK)
        xsm[k] = (k < K1) ? x1[(size_t)n * s1 + k]
                          : x2[(size_t)n * s2 + (k - K1)];
    __syncthreads();

    const float a1 = a1p[0];
    const float a2 = a2p[0];

    for (int h = tid; h < H; h += BLOCK) {
        float acc = b1[h];
        for (int k = 0; k < K; ++k) acc += xsm[k] * w1[(size_t)k * H + h];
        hsm[h] = acc > 0.f ? acc : a1 * acc;
    }
    __syncthreads();

    for (int o = tid; o < OUT; o += BLOCK) {
        float acc = b2[o];
        for (int h = 0; h < H; ++h) acc += hsm[h] * w2[(size_t)h * OUT + o];
        acc = acc > 0.f ? acc : a2 * acc;
        out[(size_t)n * out_stride + o] = acc;
    }
}

// ---------------------------------------------------------------------------
// Y[N][OUT] (bf16) = X[N][K] (f32) @ W[K][OUT] (f32)
// ---------------------------------------------------------------------------
template <int K, int OUT>
__global__ __launch_bounds__(256) void w12_gemm(
    const float* __restrict__ X, const float* __restrict__ W,
    bf16* __restrict__ Y, int N)
{
    int idx = blockIdx.x * 256 + threadIdx.x;
    if (idx >= N * OUT) return;
    int n = idx / OUT, o = idx % OUT;
    const float* xr = X + (size_t)n * K;
    float acc = 0.f;
#pragma unroll 8
    for (int k = 0; k < K; ++k) acc += xr[k] * W[(size_t)k * OUT + o];
    Y[idx] = w12_f2b(acc);
}

// ---------------------------------------------------------------------------
// CSR build (int atomics only; proven)
// ---------------------------------------------------------------------------
__global__ __launch_bounds__(256) void w12_zero_int(int* __restrict__ p, int n)
{
    int i = blockIdx.x * 256 + threadIdx.x;
    if (i < n) p[i] = 0;
}

__global__ __launch_bounds__(256) void w12_hist(
    const int* __restrict__ dst, int* __restrict__ rowp, int E)
{
    int i = blockIdx.x * 256 + threadIdx.x;
    if (i < E) atomicAdd(&rowp[dst[i] + 1], 1);
}

__global__ __launch_bounds__(256) void w12_scan(int* __restrict__ data, int n)
{
    __shared__ int buf[256];
    __shared__ int carry;
    if (threadIdx.x == 0) carry = 0;
    __syncthreads();
    for (int base = 0; base < n; base += 256) {
        int i = base + threadIdx.x;
        int v = (i < n) ? data[i] : 0;
        buf[threadIdx.x] = v;
        __syncthreads();
        for (int off = 1; off < 256; off <<= 1) {
            int t = (threadIdx.x >= off) ? buf[threadIdx.x - off] : 0;
            __syncthreads();
            buf[threadIdx.x] += t;
            __syncthreads();
        }
        int c = carry;
        if (i < n) data[i] = buf[threadIdx.x] + c;
        __syncthreads();
        if (threadIdx.x == 255) carry = c + buf[255];
        __syncthreads();
    }
}

__global__ __launch_bounds__(256) void w12_copy_int(
    const int* __restrict__ src, int* __restrict__ dstp, int n)
{
    int i = blockIdx.x * 256 + threadIdx.x;
    if (i < n) dstp[i] = src[i];
}

__global__ __launch_bounds__(256) void w12_fill(
    const int* __restrict__ src, const int* __restrict__ dst,
    int* __restrict__ curs, int* __restrict__ col, int E)
{
    int i = blockIdx.x * 256 + threadIdx.x;
    if (i >= E) return;
    int pos = atomicAdd(&curs[dst[i]], 1);
    col[pos] = src[i];
}

__global__ __launch_bounds__(256) void w12_dis(
    const int* __restrict__ rowp, float* __restrict__ dis, int n)
{
    int i = blockIdx.x * 256 + threadIdx.x;
    if (i < n) dis[i] = 1.0f / sqrtf((float)(rowp[i + 1] - rowp[i] + 1));
}

// ---------------------------------------------------------------------------
// Fused GCN aggregation (gather); f32 output; optional f32 mirror to d_out.
// ---------------------------------------------------------------------------
template <int W, bool RELU, bool FOUT>
__global__ __launch_bounds__(256) void w12_gcn(
    const int* __restrict__ rowp, const int* __restrict__ col,
    const float* __restrict__ dis, const bf16* __restrict__ h,
    const float* __restrict__ bias, float* __restrict__ out,
    float* __restrict__ fout, int N)
{
    int t = blockIdx.x * 256 + threadIdx.x;
    int n = t / W, j = t % W;
    if (n >= N) return;
    const float dn  = dis[n];
    const int   beg = rowp[n], end = rowp[n + 1];
    float acc = 0.f;
    for (int e = beg; e < end; ++e) {
        int s = col[e];
        acc += dis[s] * w12_b2f(h[(size_t)s * W + j]);
    }
    float v = dn * acc + dn * dn * w12_b2f(h[(size_t)n * W + j]) + bias[j];
    if (RELU) v = fmaxf(v, 0.f);
    out[(size_t)n * W + j] = v;
    if (FOUT) fout[(size_t)n * W + j] = v;
}

// ---------------------------------------------------------------------------
// decode: sigmoid(dot32(z[src], z[dst])); 32 lanes per edge; f32 output
// ---------------------------------------------------------------------------
__global__ __launch_bounds__(256) void w12_decode(
    const int* __restrict__ src, const int* __restrict__ dst,
    const float* __restrict__ z, float* __restrict__ out, int E)
{
    int t = blockIdx.x * 256 + threadIdx.x;
    int e = t >> 5, j = t & 31;
    if (e >= E) return;
    float v = z[(size_t)src[e] * 32 + j] * z[(size_t)dst[e] * 32 + j];
#pragma unroll
    for (int off = 16; off > 0; off >>= 1) v += __shfl_down(v, off, 32);
    if (j == 0) out[e] = 1.f / (1.f + expf(-v));
}

// ---------------------------------------------------------------------------
extern "C" void kernel_launch(void* const* d_in, const int* in_sizes, int n_in,
                              void* d_out, int out_size, void* d_ws, size_t ws_size,
                              hipStream_t stream)
{
    const float* bcat  = (const float*)d_in[0];
    const float* bdesc = (const float*)d_in[1];
    const float* pcat  = (const float*)d_in[2];
    const int*   eib   = (const int*)d_in[3];
    const int*   eip   = (const int*)d_in[4];

    const float *bc_w1=(const float*)d_in[5],  *bc_b1=(const float*)d_in[6],  *bc_a1=(const float*)d_in[7];
    const float *bc_w2=(const float*)d_in[8],  *bc_b2=(const float*)d_in[9],  *bc_a2=(const float*)d_in[10];
    const float *bd_w1=(const float*)d_in[11], *bd_b1=(const float*)d_in[12], *bd_a1=(const float*)d_in[13];
    const float *bd_w2=(const float*)d_in[14], *bd_b2=(const float*)d_in[15], *bd_a2=(const float*)d_in[16];
    const float *bf_w1=(const float*)d_in[17], *bf_b1=(const float*)d_in[18], *bf_a1=(const float*)d_in[19];
    const float *bf_w2=(const float*)d_in[20], *bf_b2=(const float*)d_in[21], *bf_a2=(const float*)d_in[22];
    const float *pc_w1=(const float*)d_in[23], *pc_b1=(const float*)d_in[24], *pc_a1=(const float*)d_in[25];
    const float *pc_w2=(const float*)d_in[26], *pc_b2=(const float*)d_in[27], *pc_a2=(const float*)d_in[28];
    const float *gb_w1=(const float*)d_in[29], *gb_b1=(const float*)d_in[30];
    const float *gb_w2=(const float*)d_in[31], *gb_b2=(const float*)d_in[32];
    const float *gp_w1=(const float*)d_in[33], *gp_b1=(const float*)d_in[34];
    const float *gp_w2=(const float*)d_in[35], *gp_b2=(const float*)d_in[36];

    const int* srcB = eib;  const int* dstB = eib + E_B;
    const int* srcP = eip;  const int* dstP = eip + E_P;

    // ws layout (proven base + swizzled-weight area at the end)
    int*   rowp = (int*)d_ws;               // 200001
    int*   curs = rowp + 200001;            // 200000
    int*   col  = curs + 200000;            // 3200000
    float* dis  = (float*)(col + 3200000);  // 200000
    float* A    = dis + 200000;             // 12800000 f32
    bf16*  Bh   = (bf16*)(A + 12800000);    // 12800000 bf16 (6.4M words)
    float* BhF  = (float*)Bh;
    float* A2   = A + 6400000;

    // swizzled weights (bf16 ushort), after the proven region (word 23,000,001)
    unsigned short* wz = (unsigned short*)((float*)d_ws + 23000001);
    unsigned short* wz_bc1 = wz;              // 128x512 = 65536
    unsigned short* wz_bc2 = wz_bc1 + 65536;  // 512x64  = 32768
    unsigned short* wz_bf1 = wz_bc2 + 32768;  // 96x512  = 49152
    unsigned short* wz_bf2 = wz_bf1 + 49152;  // 512x64  = 32768
    unsigned short* wz_pc1 = wz_bf2 + 32768;  // 416x512 = 212992
    unsigned short* wz_pc2 = wz_pc1 + 212992; // 512x64  = 32768

    // f32 outputs
    float* out_zb = (float*)d_out;          // [N_B x 32]
    float* out_ab = out_zb + 6400000;       // [E_B]
    float* out_zp = out_ab + 3200000;       // [N_P x 32]
    float* out_ap = out_zp + 3200000;       // [E_P]

    // ---- weight conversion (fragment-swizzled bf16) ----
    {
        int t1 = 4  * 32 * 64;  cvt_w<<<(t1 + 255)/256, 256, 0, stream>>>(bc_w1, wz_bc1, 110, 4,  512);
        int t2 = 16 * 4  * 64;  cvt_w<<<(t2 + 255)/256, 256, 0, stream>>>(bc_w2, wz_bc2, 512, 16, 64);
        int t3 = 3  * 32 * 64;  cvt_w<<<(t3 + 255)/256, 256, 0, stream>>>(bf_w1, wz_bf1, 96,  3,  512);
        int t4 = 16 * 4  * 64;  cvt_w<<<(t4 + 255)/256, 256, 0, stream>>>(bf_w2, wz_bf2, 512, 16, 64);
        int t5 = 13 * 32 * 64;  cvt_w<<<(t5 + 255)/256, 256, 0, stream>>>(pc_w1, wz_pc1, 401, 13, 512);
        int t6 = 16 * 4  * 64;  cvt_w<<<(t6 + 255)/256, 256, 0, stream>>>(pc_w2, wz_pc2, 512, 16, 64);
    }

    // ================= buildings: CSR =======================================
    w12_zero_int<<<(N_B + 1 + 255) / 256, 256, 0, stream>>>(rowp, N_B + 1);
    w12_hist    <<<(E_B + 255) / 256, 256, 0, stream>>>(dstB, rowp, E_B);
    w12_scan    <<<1, 256, 0, stream>>>(rowp, N_B + 1);
    w12_copy_int<<<(N_B + 255) / 256, 256, 0, stream>>>(rowp, curs, N_B);
    w12_fill    <<<(E_B + 255) / 256, 256, 0, stream>>>(srcB, dstB, curs, col, E_B);
    w12_dis     <<<(N_B + 255) / 256, 256, 0, stream>>>(rowp, dis, N_B);

    // ================= buildings: MLPs (MFMA) ===============================
    mfma_mlp<110,0,128,512,64><<<N_B/32, 256, 0, stream>>>(
        bcat,110, (const float*)nullptr,0,
        wz_bc1, bc_b1, bc_a1, wz_bc2, bc_b2, bc_a2, A);
    w12_mlp2<13,0,64,32,128><<<N_B,128,0,stream>>>(
        bdesc,13, (const float*)nullptr,0,
        bd_w1,bd_b1,bd_a1, bd_w2,bd_b2,bd_a2, BhF,32);
    mfma_mlp<64,32,96,512,64><<<N_B/32, 256, 0, stream>>>(
        A,64, BhF,32,
        wz_bf1, bf_b1, bf_a1, wz_bf2, bf_b2, bf_a2, A);

    // ================= buildings: GCN + decode ==============================
    w12_gemm<64,64><<<(N_B*64 + 255)/256, 256, 0, stream>>>(A, gb_w1, Bh, N_B);
    w12_gcn<64,true,false><<<(N_B*64 + 255)/256, 256, 0, stream>>>(
        rowp, col, dis, Bh, gb_b1, A, (float*)nullptr, N_B);
    w12_gemm<64,32><<<(N_B*32 + 255)/256, 256, 0, stream>>>(A, gb_w2, Bh, N_B);
    w12_gcn<32,false,true><<<(N_B*32 + 255)/256, 256, 0, stream>>>(
        rowp, col, dis, Bh, gb_b2, A, out_zb, N_B);

    w12_decode<<<(E_B*32 + 255)/256, 256, 0, stream>>>(srcB, dstB, A, out_ab, E_B);

    // ================= POIs =================================================
    w12_zero_int<<<(N_P + 1 + 255) / 256, 256, 0, stream>>>(rowp, N_P + 1);
    w12_hist    <<<(E_P + 255) / 256, 256, 0, stream>>>(dstP, rowp, E_P);
    w12_scan    <<<1, 256, 0, stream>>>(rowp, N_P + 1);
    w12_copy_int<<<(N_P + 255) / 256, 256, 0, stream>>>(rowp, curs, N_P);
    w12_fill    <<<(E_P + 255) / 256, 256, 0, stream>>>(srcP, dstP, curs, col, E_P);
    w12_dis     <<<(N_P + 255) / 256, 256, 0, stream>>>(rowp, dis, N_P);

    mfma_mlp<401,0,416,512,64><<<N_P/32, 256, 0, stream>>>(
        pcat,401, (const float*)nullptr,0,
        wz_pc1, pc_b1, pc_a1, wz_pc2, pc_b2, pc_a2, A2);

    w12_gemm<64,64><<<(N_P*64 + 255)/256, 256, 0, stream>>>(A2, gp_w1, Bh, N_P);
    w12_gcn<64,true,false><<<(N_P*64 + 255)/256, 256, 0, stream>>>(
        rowp, col, dis, Bh, gp_b1, A2, (float*)nullptr, N_P);
    w12_gemm<64,32><<<(N_P*32 + 255)/256, 256, 0, stream>>>(A2, gp_w2, Bh, N_P);
    w12_gcn<32,false,true><<<(N_P*32 + 255)/256, 256, 0, stream>>>(
        rowp, col, dis, Bh, gp_b2, A2, out_zp, N_P);

    w12_decode<<<(E_P*32 + 255)/256, 256, 0, stream>>>(srcP, dstP, A2, out_ap, E_P);
}

// Round 14
// 2750.869 us; speedup vs baseline: 3.9977x; 1.4935x over previous
//
#include <hip/hip_runtime.h>
#include <hip/hip_bf16.h>

using bf16 = __hip_bfloat16;
typedef __attribute__((ext_vector_type(8))) short bf16x8_t;
typedef __attribute__((ext_vector_type(4))) float f32x4_t;

#define N_B 200000
#define E_B 3200000
#define N_P 100000
#define E_P 1600000

__device__ __forceinline__ bf16  w12_f2b(float v) { return __float2bfloat16(v); }
__device__ __forceinline__ float w12_b2f(bf16 v)  { return __bfloat162float(v); }

// f32 -> bf16 bit pattern, round-to-nearest-even
__device__ __forceinline__ unsigned short f2bits(float f)
{
    union { float f; unsigned u; } v; v.f = f;
    unsigned u = v.u;
    unsigned r = (u + 0x7FFFu + ((u >> 16) & 1u)) >> 16;
    return (unsigned short)r;
}

// ---------------------------------------------------------------------------
// Weight converter: w [K][H] f32 -> fragment-swizzled bf16
// ---------------------------------------------------------------------------
__global__ __launch_bounds__(256) void cvt_w(
    const float* __restrict__ w, unsigned short* __restrict__ dst,
    int K, int ktiles, int H)
{
    int total = ktiles * (H / 16) * 64;
    int idx = blockIdx.x * 256 + threadIdx.x;
    if (idx >= total) return;
    int lane = idx & 63;
    int t    = idx >> 6;
    int nt   = t % (H / 16);
    int kt   = t / (H / 16);
    int kg   = lane >> 4, cl = lane & 15;
#pragma unroll
    for (int j = 0; j < 8; ++j) {
        int k = kt * 32 + kg * 8 + j;
        float v = (k < K) ? w[(size_t)k * H + nt * 16 + cl] : 0.f;
        dst[(size_t)idx * 8 + j] = f2bits(v);
    }
}

// ---------------------------------------------------------------------------
// MFMA fused 2-layer MLP (proven round-13 structure)
// ---------------------------------------------------------------------------
template <int K1, int K2, int KP, int H, int OUT>
__global__ __launch_bounds__(256) void mfma_mlp(
    const float* __restrict__ x1, int s1,
    const float* __restrict__ x2, int s2,
    const unsigned short* __restrict__ w1s, const float* __restrict__ b1, const float* __restrict__ a1p,
    const unsigned short* __restrict__ w2s, const float* __restrict__ b2, const float* __restrict__ a2p,
    float* __restrict__ out)
{
    constexpr int PAD = 8;
    constexpr int XS  = KP + PAD;
    constexpr int HS  = H + PAD;
    constexpr int NT1 = H / 16;
    constexpr int TP1 = NT1 / 2;
    constexpr int NT2 = OUT / 16;
    constexpr int TP2 = NT2 / 2;

    __shared__ unsigned short xs[32 * XS];
    __shared__ unsigned short hs[32 * HS];

    const int tid = threadIdx.x;
    const int n0  = blockIdx.x * 32;

    for (int i = tid; i < 32 * KP; i += 256) {
        int n = i / KP, k = i - n * KP;
        float v = 0.f;
        if (k < K1)            v = x1[(size_t)(n0 + n) * s1 + k];
        else if (k < K1 + K2)  v = x2[(size_t)(n0 + n) * s2 + (k - K1)];
        xs[n * XS + k] = f2bits(v);
    }
    __syncthreads();

    const float a1 = a1p[0], a2 = a2p[0];
    const int wv = tid >> 6, lane = tid & 63;
    const int m = wv & 1, wg = wv >> 1;
    const int kg = lane >> 4, cl = lane & 15;

    const int ntb = wg * TP1;
    f32x4_t acc[TP1];
    const f32x4_t zero = {0.f, 0.f, 0.f, 0.f};
#pragma unroll
    for (int i = 0; i < TP1; ++i) acc[i] = zero;

    for (int kt = 0; kt < KP / 32; ++kt) {
        bf16x8_t a = *(const bf16x8_t*)(xs + (m * 16 + cl) * XS + kt * 32 + kg * 8);
#pragma unroll
        for (int i = 0; i < TP1; ++i) {
            bf16x8_t b = *(const bf16x8_t*)(w1s + ((size_t)(kt * NT1 + ntb + i) * 64 + lane) * 8);
            acc[i] = __builtin_amdgcn_mfma_f32_16x16x32_bf16(a, b, acc[i], 0, 0, 0);
        }
    }
#pragma unroll
    for (int i = 0; i < TP1; ++i) {
        int c = (ntb + i) * 16 + cl;
        float bb = b1[c];
#pragma unroll
        for (int r = 0; r < 4; ++r) {
            float v = acc[i][r] + bb;
            v = v > 0.f ? v : a1 * v;
            hs[(m * 16 + kg * 4 + r) * HS + c] = f2bits(v);
        }
    }
    __syncthreads();

    const int ntb2 = wg * TP2;
    f32x4_t acc2[TP2];
#pragma unroll
    for (int i = 0; i < TP2; ++i) acc2[i] = zero;

    for (int kt = 0; kt < H / 32; ++kt) {
        bf16x8_t a = *(const bf16x8_t*)(hs + (m * 16 + cl) * HS + kt * 32 + kg * 8);
#pragma unroll
        for (int i = 0; i < TP2; ++i) {
            bf16x8_t b = *(const bf16x8_t*)(w2s + ((size_t)(kt * NT2 + ntb2 + i) * 64 + lane) * 8);
            acc2[i] = __builtin_amdgcn_mfma_f32_16x16x32_bf16(a, b, acc2[i], 0, 0, 0);
        }
    }
#pragma unroll
    for (int i = 0; i < TP2; ++i) {
        int c = (ntb2 + i) * 16 + cl;
        float bb = b2[c];
#pragma unroll
        for (int r = 0; r < 4; ++r) {
            float v = acc2[i][r] + bb;
            v = v > 0.f ? v : a2 * v;
            out[(size_t)(n0 + m * 16 + kg * 4 + r) * OUT + c] = v;
        }
    }
}

// ---------------------------------------------------------------------------
// Y[N][OUT] (bf16) = X[N][K] (f32) @ W[K][OUT] (f32)
// ---------------------------------------------------------------------------
template <int K, int OUT>
__global__ __launch_bounds__(256) void w12_gemm(
    const float* __restrict__ X, const float* __restrict__ W,
    bf16* __restrict__ Y, int N)
{
    int idx = blockIdx.x * 256 + threadIdx.x;
    if (idx >= N * OUT) return;
    int n = idx / OUT, o = idx % OUT;
    const float* xr = X + (size_t)n * K;
    float acc = 0.f;
#pragma unroll 8
    for (int k = 0; k < K; ++k) acc += xr[k] * W[(size_t)k * OUT + o];
    Y[idx] = w12_f2b(acc);
}

// ---------------------------------------------------------------------------
// CSR build
// ---------------------------------------------------------------------------
__global__ __launch_bounds__(256) void w12_zero_int(int* __restrict__ p, int n)
{
    int i = blockIdx.x * 256 + threadIdx.x;
    if (i < n) p[i] = 0;
}

__global__ __launch_bounds__(256) void w12_hist(
    const int* __restrict__ dst, int* __restrict__ rowp, int E)
{
    int i = blockIdx.x * 256 + threadIdx.x;
    if (i < E) atomicAdd(&rowp[dst[i] + 1], 1);
}

// single-block inclusive scan (proven) — used only for small block-sum arrays
__global__ __launch_bounds__(256) void w12_scan(int* __restrict__ data, int n)
{
    __shared__ int buf[256];
    __shared__ int carry;
    if (threadIdx.x == 0) carry = 0;
    __syncthreads();
    for (int base = 0; base < n; base += 256) {
        int i = base + threadIdx.x;
        int v = (i < n) ? data[i] : 0;
        buf[threadIdx.x] = v;
        __syncthreads();
        for (int off = 1; off < 256; off <<= 1) {
            int t = (threadIdx.x >= off) ? buf[threadIdx.x - off] : 0;
            __syncthreads();
            buf[threadIdx.x] += t;
            __syncthreads();
        }
        int c = carry;
        if (i < n) data[i] = buf[threadIdx.x] + c;
        __syncthreads();
        if (threadIdx.x == 255) carry = c + buf[255];
        __syncthreads();
    }
}

// ---- parallel 3-phase scan: 2048 elems per block (256 thr x 8) ----
#define SCAN_CHUNK 2048

__global__ __launch_bounds__(256) void scan_p1(
    const int* __restrict__ data, int n, int* __restrict__ bsum)
{
    __shared__ int sm[256];
    int base = blockIdx.x * SCAN_CHUNK;
    int s = 0;
    for (int i = threadIdx.x; i < SCAN_CHUNK; i += 256) {
        int idx = base + i;
        s += (idx < n) ? data[idx] : 0;
    }
    sm[threadIdx.x] = s;
    __syncthreads();
    for (int off = 128; off > 0; off >>= 1) {
        if (threadIdx.x < off) sm[threadIdx.x] += sm[threadIdx.x + off];
        __syncthreads();
    }
    if (threadIdx.x == 0) bsum[blockIdx.x] = sm[0];
}

__global__ __launch_bounds__(256) void scan_p3(
    int* __restrict__ data, int n, const int* __restrict__ bsum_scanned)
{
    __shared__ int tsum[256];
    int base  = blockIdx.x * SCAN_CHUNK;
    int tbase = base + threadIdx.x * 8;
    int vals[8];
    int s = 0;
#pragma unroll
    for (int j = 0; j < 8; ++j) {
        int idx = tbase + j;
        int v = (idx < n) ? data[idx] : 0;
        vals[j] = v; s += v;
    }
    tsum[threadIdx.x] = s;
    __syncthreads();
    for (int off = 1; off < 256; off <<= 1) {
        int t = (threadIdx.x >= off) ? tsum[threadIdx.x - off] : 0;
        __syncthreads();
        tsum[threadIdx.x] += t;
        __syncthreads();
    }
    int offset = (blockIdx.x > 0 ? bsum_scanned[blockIdx.x - 1] : 0)
               + (threadIdx.x > 0 ? tsum[threadIdx.x - 1] : 0);
    int run = offset;
#pragma unroll
    for (int j = 0; j < 8; ++j) {
        int idx = tbase + j;
        run += vals[j];
        if (idx < n) data[idx] = run;
    }
}

__global__ __launch_bounds__(256) void w12_copy_int(
    const int* __restrict__ src, int* __restrict__ dstp, int n)
{
    int i = blockIdx.x * 256 + threadIdx.x;
    if (i < n) dstp[i] = src[i];
}

__global__ __launch_bounds__(256) void w12_fill(
    const int* __restrict__ src, const int* __restrict__ dst,
    int* __restrict__ curs, int* __restrict__ col, int E)
{
    int i = blockIdx.x * 256 + threadIdx.x;
    if (i >= E) return;
    int pos = atomicAdd(&curs[dst[i]], 1);
    col[pos] = src[i];
}

__global__ __launch_bounds__(256) void w12_dis(
    const int* __restrict__ rowp, float* __restrict__ dis, int n)
{
    int i = blockIdx.x * 256 + threadIdx.x;
    if (i < n) dis[i] = 1.0f / sqrtf((float)(rowp[i + 1] - rowp[i] + 1));
}

// ---------------------------------------------------------------------------
// Fused GCN aggregation (gather); f32 output; optional f32 mirror to d_out.
// ---------------------------------------------------------------------------
template <int W, bool RELU, bool FOUT>
__global__ __launch_bounds__(256) void w12_gcn(
    const int* __restrict__ rowp, const int* __restrict__ col,
    const float* __restrict__ dis, const bf16* __restrict__ h,
    const float* __restrict__ bias, float* __restrict__ out,
    float* __restrict__ fout, int N)
{
    int t = blockIdx.x * 256 + threadIdx.x;
    int n = t / W, j = t % W;
    if (n >= N) return;
    const float dn  = dis[n];
    const int   beg = rowp[n], end = rowp[n + 1];
    float acc = 0.f;
    for (int e = beg; e < end; ++e) {
        int s = col[e];
        acc += dis[s] * w12_b2f(h[(size_t)s * W + j]);
    }
    float v = dn * acc + dn * dn * w12_b2f(h[(size_t)n * W + j]) + bias[j];
    if (RELU) v = fmaxf(v, 0.f);
    out[(size_t)n * W + j] = v;
    if (FOUT) fout[(size_t)n * W + j] = v;
}

// ---------------------------------------------------------------------------
// decode: sigmoid(dot32(z[src], z[dst])); 32 lanes per edge; f32 output
// ---------------------------------------------------------------------------
__global__ __launch_bounds__(256) void w12_decode(
    const int* __restrict__ src, const int* __restrict__ dst,
    const float* __restrict__ z, float* __restrict__ out, int E)
{
    int t = blockIdx.x * 256 + threadIdx.x;
    int e = t >> 5, j = t & 31;
    if (e >= E) return;
    float v = z[(size_t)src[e] * 32 + j] * z[(size_t)dst[e] * 32 + j];
#pragma unroll
    for (int off = 16; off > 0; off >>= 1) v += __shfl_down(v, off, 32);
    if (j == 0) out[e] = 1.f / (1.f + expf(-v));
}

// ---------------------------------------------------------------------------
extern "C" void kernel_launch(void* const* d_in, const int* in_sizes, int n_in,
                              void* d_out, int out_size, void* d_ws, size_t ws_size,
                              hipStream_t stream)
{
    const float* bcat  = (const float*)d_in[0];
    const float* bdesc = (const float*)d_in[1];
    const float* pcat  = (const float*)d_in[2];
    const int*   eib   = (const int*)d_in[3];
    const int*   eip   = (const int*)d_in[4];

    const float *bc_w1=(const float*)d_in[5],  *bc_b1=(const float*)d_in[6],  *bc_a1=(const float*)d_in[7];
    const float *bc_w2=(const float*)d_in[8],  *bc_b2=(const float*)d_in[9],  *bc_a2=(const float*)d_in[10];
    const float *bd_w1=(const float*)d_in[11], *bd_b1=(const float*)d_in[12], *bd_a1=(const float*)d_in[13];
    const float *bd_w2=(const float*)d_in[14], *bd_b2=(const float*)d_in[15], *bd_a2=(const float*)d_in[16];
    const float *bf_w1=(const float*)d_in[17], *bf_b1=(const float*)d_in[18], *bf_a1=(const float*)d_in[19];
    const float *bf_w2=(const float*)d_in[20], *bf_b2=(const float*)d_in[21], *bf_a2=(const float*)d_in[22];
    const float *pc_w1=(const float*)d_in[23], *pc_b1=(const float*)d_in[24], *pc_a1=(const float*)d_in[25];
    const float *pc_w2=(const float*)d_in[26], *pc_b2=(const float*)d_in[27], *pc_a2=(const float*)d_in[28];
    const float *gb_w1=(const float*)d_in[29], *gb_b1=(const float*)d_in[30];
    const float *gb_w2=(const float*)d_in[31], *gb_b2=(const float*)d_in[32];
    const float *gp_w1=(const float*)d_in[33], *gp_b1=(const float*)d_in[34];
    const float *gp_w2=(const float*)d_in[35], *gp_b2=(const float*)d_in[36];

    const int* srcB = eib;  const int* dstB = eib + E_B;
    const int* srcP = eip;  const int* dstP = eip + E_P;

    int*   rowp = (int*)d_ws;               // 200001
    int*   curs = rowp + 200001;            // 200000
    int*   col  = curs + 200000;            // 3200000
    float* dis  = (float*)(col + 3200000);  // 200000
    float* A    = dis + 200000;             // 12800000 f32
    bf16*  Bh   = (bf16*)(A + 12800000);    // 12800000 bf16 (6.4M words)
    float* BhF  = (float*)Bh;
    float* A2   = A + 6400000;

    // swizzled weights + scan scratch after the proven region
    unsigned short* wz = (unsigned short*)((float*)d_ws + 23000001);
    unsigned short* wz_bc1 = wz;              // 65536
    unsigned short* wz_bc2 = wz_bc1 + 65536;  // 32768
    unsigned short* wz_bf1 = wz_bc2 + 32768;  // 49152
    unsigned short* wz_bf2 = wz_bf1 + 49152;  // 32768
    unsigned short* wz_pc1 = wz_bf2 + 32768;  // 212992
    unsigned short* wz_pc2 = wz_pc1 + 212992; // 32768
    unsigned short* wz_bd1 = wz_pc2 + 32768;  // 2048  (13x64 -> ktiles=1, H=64)
    unsigned short* wz_bd2 = wz_bd1 + 2048;   // 2048  (64x32 -> ktiles=2, H=32)
    int* bsum = (int*)(wz_bd2 + 2048);        // 1024 ints scan scratch

    float* out_zb = (float*)d_out;          // [N_B x 32]
    float* out_ab = out_zb + 6400000;       // [E_B]
    float* out_zp = out_ab + 3200000;       // [N_P x 32]
    float* out_ap = out_zp + 3200000;       // [E_P]

    // ---- weight conversion ----
    {
        int t1 = 4  * 32 * 64;  cvt_w<<<(t1 + 255)/256, 256, 0, stream>>>(bc_w1, wz_bc1, 110, 4,  512);
        int t2 = 16 * 4  * 64;  cvt_w<<<(t2 + 255)/256, 256, 0, stream>>>(bc_w2, wz_bc2, 512, 16, 64);
        int t3 = 3  * 32 * 64;  cvt_w<<<(t3 + 255)/256, 256, 0, stream>>>(bf_w1, wz_bf1, 96,  3,  512);
        int t4 = 16 * 4  * 64;  cvt_w<<<(t4 + 255)/256, 256, 0, stream>>>(bf_w2, wz_bf2, 512, 16, 64);
        int t5 = 13 * 32 * 64;  cvt_w<<<(t5 + 255)/256, 256, 0, stream>>>(pc_w1, wz_pc1, 401, 13, 512);
        int t6 = 16 * 4  * 64;  cvt_w<<<(t6 + 255)/256, 256, 0, stream>>>(pc_w2, wz_pc2, 512, 16, 64);
        int t7 = 1  * 4  * 64;  cvt_w<<<(t7 + 255)/256, 256, 0, stream>>>(bd_w1, wz_bd1, 13,  1,  64);
        int t8 = 2  * 2  * 64;  cvt_w<<<(t8 + 255)/256, 256, 0, stream>>>(bd_w2, wz_bd2, 64,  2,  32);
    }

    const int nsb_B = (N_B + 1 + SCAN_CHUNK - 1) / SCAN_CHUNK;   // 98
    const int nsb_P = (N_P + 1 + SCAN_CHUNK - 1) / SCAN_CHUNK;   // 49

    // ================= buildings: CSR =======================================
    w12_zero_int<<<(N_B + 1 + 255) / 256, 256, 0, stream>>>(rowp, N_B + 1);
    w12_hist    <<<(E_B + 255) / 256, 256, 0, stream>>>(dstB, rowp, E_B);
    scan_p1     <<<nsb_B, 256, 0, stream>>>(rowp, N_B + 1, bsum);
    w12_scan    <<<1, 256, 0, stream>>>(bsum, nsb_B);
    scan_p3     <<<nsb_B, 256, 0, stream>>>(rowp, N_B + 1, bsum);
    w12_copy_int<<<(N_B + 255) / 256, 256, 0, stream>>>(rowp, curs, N_B);
    w12_fill    <<<(E_B + 255) / 256, 256, 0, stream>>>(srcB, dstB, curs, col, E_B);
    w12_dis     <<<(N_B + 255) / 256, 256, 0, stream>>>(rowp, dis, N_B);

    // ================= buildings: MLPs (all MFMA) ===========================
    mfma_mlp<110,0,128,512,64><<<N_B/32, 256, 0, stream>>>(
        bcat,110, (const float*)nullptr,0,
        wz_bc1, bc_b1, bc_a1, wz_bc2, bc_b2, bc_a2, A);
    mfma_mlp<13,0,32,64,32><<<N_B/32, 256, 0, stream>>>(
        bdesc,13, (const float*)nullptr,0,
        wz_bd1, bd_b1, bd_a1, wz_bd2, bd_b2, bd_a2, BhF);
    mfma_mlp<64,32,96,512,64><<<N_B/32, 256, 0, stream>>>(
        A,64, BhF,32,
        wz_bf1, bf_b1, bf_a1, wz_bf2, bf_b2, bf_a2, A);

    // ================= buildings: GCN + decode ==============================
    w12_gemm<64,64><<<(N_B*64 + 255)/256, 256, 0, stream>>>(A, gb_w1, Bh, N_B);
    w12_gcn<64,true,false><<<(N_B*64 + 255)/256, 256, 0, stream>>>(
        rowp, col, dis, Bh, gb_b1, A, (float*)nullptr, N_B);
    w12_gemm<64,32><<<(N_B*32 + 255)/256, 256, 0, stream>>>(A, gb_w2, Bh, N_B);
    w12_gcn<32,false,true><<<(N_B*32 + 255)/256, 256, 0, stream>>>(
        rowp, col, dis, Bh, gb_b2, A, out_zb, N_B);

    w12_decode<<<(E_B*32 + 255)/256, 256, 0, stream>>>(srcB, dstB, A, out_ab, E_B);

    // ================= POIs =================================================
    w12_zero_int<<<(N_P + 1 + 255) / 256, 256, 0, stream>>>(rowp, N_P + 1);
    w12_hist    <<<(E_P + 255) / 256, 256, 0, stream>>>(dstP, rowp, E_P);
    scan_p1     <<<nsb_P, 256, 0, stream>>>(rowp, N_P + 1, bsum);
    w12_scan    <<<1, 256, 0, stream>>>(bsum, nsb_P);
    scan_p3     <<<nsb_P, 256, 0, stream>>>(rowp, N_P + 1, bsum);
    w12_copy_int<<<(N_P + 255) / 256, 256, 0, stream>>>(rowp, curs, N_P);
    w12_fill    <<<(E_P + 255) / 256, 256, 0, stream>>>(srcP, dstP, curs, col, E_P);
    w12_dis     <<<(N_P + 255) / 256, 256, 0, stream>>>(rowp, dis, N_P);

    mfma_mlp<401,0,416,512,64><<<N_P/32, 256, 0, stream>>>(
        pcat,401, (const float*)nullptr,0,
        wz_pc1, pc_b1, pc_a1, wz_pc2, pc_b2, pc_a2, A2);

    w12_gemm<64,64><<<(N_P*64 + 255)/256, 256, 0, stream>>>(A2, gp_w1, Bh, N_P);
    w12_gcn<64,true,false><<<(N_P*64 + 255)/256, 256, 0, stream>>>(
        rowp, col, dis, Bh, gp_b1, A2, (float*)nullptr, N_P);
    w12_gemm<64,32><<<(N_P*32 + 255)/256, 256, 0, stream>>>(A2, gp_w2, Bh, N_P);
    w12_gcn<32,false,true><<<(N_P*32 + 255)/256, 256, 0, stream>>>(
        rowp, col, dis, Bh, gp_b2, A2, out_zp, N_P);

    w12_decode<<<(E_P*32 + 255)/256, 256, 0, stream>>>(srcP, dstP, A2, out_ap, E_P);
}

// Round 15
// 2342.262 us; speedup vs baseline: 4.6951x; 1.1744x over previous
//
#include <hip/hip_runtime.h>
#include <hip/hip_bf16.h>

using bf16 = __hip_bfloat16;
typedef __attribute__((ext_vector_type(8))) short bf16x8_t;
typedef __attribute__((ext_vector_type(4))) float f32x4_t;

#define N_B 200000
#define E_B 3200000
#define N_P 100000
#define E_P 1600000

__device__ __forceinline__ bf16  w12_f2b(float v) { return __float2bfloat16(v); }
__device__ __forceinline__ float w12_b2f(bf16 v)  { return __bfloat162float(v); }

// f32 -> bf16 bit pattern, round-to-nearest-even
__device__ __forceinline__ unsigned short f2bits(float f)
{
    union { float f; unsigned u; } v; v.f = f;
    unsigned u = v.u;
    unsigned r = (u + 0x7FFFu + ((u >> 16) & 1u)) >> 16;
    return (unsigned short)r;
}

// ---------------------------------------------------------------------------
// Weight converter: w [K][H] f32 -> fragment-swizzled bf16 (proven)
// ---------------------------------------------------------------------------
__global__ __launch_bounds__(256) void cvt_w(
    const float* __restrict__ w, unsigned short* __restrict__ dst,
    int K, int ktiles, int H)
{
    int total = ktiles * (H / 16) * 64;
    int idx = blockIdx.x * 256 + threadIdx.x;
    if (idx >= total) return;
    int lane = idx & 63;
    int t    = idx >> 6;
    int nt   = t % (H / 16);
    int kt   = t / (H / 16);
    int kg   = lane >> 4, cl = lane & 15;
#pragma unroll
    for (int j = 0; j < 8; ++j) {
        int k = kt * 32 + kg * 8 + j;
        float v = (k < K) ? w[(size_t)k * H + nt * 16 + cl] : 0.f;
        dst[(size_t)idx * 8 + j] = f2bits(v);
    }
}

// ---------------------------------------------------------------------------
// MFMA fused 2-layer MLP, A-operand direct from global (no xs LDS).
// 32 nodes/block, 4 waves. x = concat(x1[K1], x2[K2]); KP = padded K.
// Layer-1 reads all precede layer-2 writes -> in-place out==x1 safe.
// ---------------------------------------------------------------------------
template <int K1, int K2, int KP, int H, int OUT>
__global__ __launch_bounds__(256) void mlp_g(
    const float* __restrict__ x1, int s1,
    const float* __restrict__ x2, int s2,
    const unsigned short* __restrict__ w1s, const float* __restrict__ b1, const float* __restrict__ a1p,
    const unsigned short* __restrict__ w2s, const float* __restrict__ b2, const float* __restrict__ a2p,
    float* __restrict__ out)
{
    constexpr int PAD = 8;
    constexpr int HS  = H + PAD;             // 16B-aligned row stride
    constexpr int NT1 = H / 16, TP1 = NT1 / 2;
    constexpr int NT2 = OUT / 16, TP2 = NT2 / 2;

    __shared__ unsigned short hs[32 * HS];

    const int tid = threadIdx.x;
    const int n0  = blockIdx.x * 32;
    const int wv = tid >> 6, lane = tid & 63;
    const int m = wv & 1, wg = wv >> 1;
    const int kg = lane >> 4, cl = lane & 15;
    const int arow = n0 + m * 16 + cl;
    const float a1 = a1p[0], a2 = a2p[0];

    const float* r1 = x1 + (size_t)arow * s1;
    const float* r2 = (K2 > 0) ? (x2 + (size_t)arow * s2) : x1;

    // ---------------- layer 1 ----------------
    const int ntb = wg * TP1;
    f32x4_t acc[TP1];
    const f32x4_t zero = {0.f, 0.f, 0.f, 0.f};
#pragma unroll
    for (int i = 0; i < TP1; ++i) acc[i] = zero;

    for (int kt = 0; kt < KP / 32; ++kt) {
        const int k0 = kt * 32 + kg * 8;
        bf16x8_t a;
#pragma unroll
        for (int j = 0; j < 8; ++j) {
            int k = k0 + j;
            float v = 0.f;
            if (k < K1)                          v = r1[k];
            else if (K2 > 0 && k < K1 + K2)      v = r2[k - K1];
            a[j] = (short)f2bits(v);
        }
#pragma unroll
        for (int i = 0; i < TP1; ++i) {
            bf16x8_t b = *(const bf16x8_t*)(w1s + ((size_t)(kt * NT1 + ntb + i) * 64 + lane) * 8);
            acc[i] = __builtin_amdgcn_mfma_f32_16x16x32_bf16(a, b, acc[i], 0, 0, 0);
        }
    }
#pragma unroll
    for (int i = 0; i < TP1; ++i) {
        int c = (ntb + i) * 16 + cl;
        float bb = b1[c];
#pragma unroll
        for (int r = 0; r < 4; ++r) {
            float v = acc[i][r] + bb;
            v = v > 0.f ? v : a1 * v;
            hs[(m * 16 + kg * 4 + r) * HS + c] = f2bits(v);
        }
    }
    __syncthreads();

    // ---------------- layer 2 ----------------
    const int ntb2 = wg * TP2;
    f32x4_t acc2[TP2];
#pragma unroll
    for (int i = 0; i < TP2; ++i) acc2[i] = zero;

    for (int kt = 0; kt < H / 32; ++kt) {
        bf16x8_t a = *(const bf16x8_t*)(hs + (m * 16 + cl) * HS + kt * 32 + kg * 8);
#pragma unroll
        for (int i = 0; i < TP2; ++i) {
            bf16x8_t b = *(const bf16x8_t*)(w2s + ((size_t)(kt * NT2 + ntb2 + i) * 64 + lane) * 8);
            acc2[i] = __builtin_amdgcn_mfma_f32_16x16x32_bf16(a, b, acc2[i], 0, 0, 0);
        }
    }
#pragma unroll
    for (int i = 0; i < TP2; ++i) {
        int c = (ntb2 + i) * 16 + cl;
        float bb = b2[c];
#pragma unroll
        for (int r = 0; r < 4; ++r) {
            float v = acc2[i][r] + bb;
            v = v > 0.f ? v : a2 * v;
            out[(size_t)(n0 + m * 16 + kg * 4 + r) * OUT + c] = v;
        }
    }
}

// ---------------------------------------------------------------------------
// Y[N][OUT] (bf16) = X[N][K] (f32) @ W[K][OUT] (f32)
// ---------------------------------------------------------------------------
template <int K, int OUT>
__global__ __launch_bounds__(256) void w12_gemm(
    const float* __restrict__ X, const float* __restrict__ W,
    bf16* __restrict__ Y, int N)
{
    int idx = blockIdx.x * 256 + threadIdx.x;
    if (idx >= N * OUT) return;
    int n = idx / OUT, o = idx % OUT;
    const float* xr = X + (size_t)n * K;
    float acc = 0.f;
#pragma unroll 8
    for (int k = 0; k < K; ++k) acc += xr[k] * W[(size_t)k * OUT + o];
    Y[idx] = w12_f2b(acc);
}

// ---------------------------------------------------------------------------
// CSR build (proven)
// ---------------------------------------------------------------------------
__global__ __launch_bounds__(256) void w12_zero_int(int* __restrict__ p, int n)
{
    int i = blockIdx.x * 256 + threadIdx.x;
    if (i < n) p[i] = 0;
}

__global__ __launch_bounds__(256) void w12_hist(
    const int* __restrict__ dst, int* __restrict__ rowp, int E)
{
    int i = blockIdx.x * 256 + threadIdx.x;
    if (i < E) atomicAdd(&rowp[dst[i] + 1], 1);
}

__global__ __launch_bounds__(256) void w12_scan(int* __restrict__ data, int n)
{
    __shared__ int buf[256];
    __shared__ int carry;
    if (threadIdx.x == 0) carry = 0;
    __syncthreads();
    for (int base = 0; base < n; base += 256) {
        int i = base + threadIdx.x;
        int v = (i < n) ? data[i] : 0;
        buf[threadIdx.x] = v;
        __syncthreads();
        for (int off = 1; off < 256; off <<= 1) {
            int t = (threadIdx.x >= off) ? buf[threadIdx.x - off] : 0;
            __syncthreads();
            buf[threadIdx.x] += t;
            __syncthreads();
        }
        int c = carry;
        if (i < n) data[i] = buf[threadIdx.x] + c;
        __syncthreads();
        if (threadIdx.x == 255) carry = c + buf[255];
        __syncthreads();
    }
}

#define SCAN_CHUNK 2048

__global__ __launch_bounds__(256) void scan_p1(
    const int* __restrict__ data, int n, int* __restrict__ bsum)
{
    __shared__ int sm[256];
    int base = blockIdx.x * SCAN_CHUNK;
    int s = 0;
    for (int i = threadIdx.x; i < SCAN_CHUNK; i += 256) {
        int idx = base + i;
        s += (idx < n) ? data[idx] : 0;
    }
    sm[threadIdx.x] = s;
    __syncthreads();
    for (int off = 128; off > 0; off >>= 1) {
        if (threadIdx.x < off) sm[threadIdx.x] += sm[threadIdx.x + off];
        __syncthreads();
    }
    if (threadIdx.x == 0) bsum[blockIdx.x] = sm[0];
}

__global__ __launch_bounds__(256) void scan_p3(
    int* __restrict__ data, int n, const int* __restrict__ bsum_scanned)
{
    __shared__ int tsum[256];
    int base  = blockIdx.x * SCAN_CHUNK;
    int tbase = base + threadIdx.x * 8;
    int vals[8];
    int s = 0;
#pragma unroll
    for (int j = 0; j < 8; ++j) {
        int idx = tbase + j;
        int v = (idx < n) ? data[idx] : 0;
        vals[j] = v; s += v;
    }
    tsum[threadIdx.x] = s;
    __syncthreads();
    for (int off = 1; off < 256; off <<= 1) {
        int t = (threadIdx.x >= off) ? tsum[threadIdx.x - off] : 0;
        __syncthreads();
        tsum[threadIdx.x] += t;
        __syncthreads();
    }
    int offset = (blockIdx.x > 0 ? bsum_scanned[blockIdx.x - 1] : 0)
               + (threadIdx.x > 0 ? tsum[threadIdx.x - 1] : 0);
    int run = offset;
#pragma unroll
    for (int j = 0; j < 8; ++j) {
        int idx = tbase + j;
        run += vals[j];
        if (idx < n) data[idx] = run;
    }
}

__global__ __launch_bounds__(256) void w12_copy_int(
    const int* __restrict__ src, int* __restrict__ dstp, int n)
{
    int i = blockIdx.x * 256 + threadIdx.x;
    if (i < n) dstp[i] = src[i];
}

__global__ __launch_bounds__(256) void w12_fill(
    const int* __restrict__ src, const int* __restrict__ dst,
    int* __restrict__ curs, int* __restrict__ col, int E)
{
    int i = blockIdx.x * 256 + threadIdx.x;
    if (i >= E) return;
    int pos = atomicAdd(&curs[dst[i]], 1);
    col[pos] = src[i];
}

__global__ __launch_bounds__(256) void w12_dis(
    const int* __restrict__ rowp, float* __restrict__ dis, int n)
{
    int i = blockIdx.x * 256 + threadIdx.x;
    if (i < n) dis[i] = 1.0f / sqrtf((float)(rowp[i + 1] - rowp[i] + 1));
}

// ---------------------------------------------------------------------------
// Fused GCN aggregation (gather), 4-way edge unroll for MLP latency hiding.
// ---------------------------------------------------------------------------
template <int W, bool RELU, bool FOUT>
__global__ __launch_bounds__(256) void w12_gcn(
    const int* __restrict__ rowp, const int* __restrict__ col,
    const float* __restrict__ dis, const bf16* __restrict__ h,
    const float* __restrict__ bias, float* __restrict__ out,
    float* __restrict__ fout, int N)
{
    int t = blockIdx.x * 256 + threadIdx.x;
    int n = t / W, j = t % W;
    if (n >= N) return;
    const float dn  = dis[n];
    const int   beg = rowp[n], end = rowp[n + 1];
    float acc = 0.f;
    int e = beg;
    for (; e + 4 <= end; e += 4) {
        int s0 = col[e], s1 = col[e + 1], s2 = col[e + 2], s3 = col[e + 3];
        float d0 = dis[s0], d1 = dis[s1], d2 = dis[s2], d3 = dis[s3];
        float h0 = w12_b2f(h[(size_t)s0 * W + j]);
        float h1 = w12_b2f(h[(size_t)s1 * W + j]);
        float h2 = w12_b2f(h[(size_t)s2 * W + j]);
        float h3 = w12_b2f(h[(size_t)s3 * W + j]);
        acc += d0 * h0 + d1 * h1 + d2 * h2 + d3 * h3;
    }
    for (; e < end; ++e) {
        int s = col[e];
        acc += dis[s] * w12_b2f(h[(size_t)s * W + j]);
    }
    float v = dn * acc + dn * dn * w12_b2f(h[(size_t)n * W + j]) + bias[j];
    if (RELU) v = fmaxf(v, 0.f);
    out[(size_t)n * W + j] = v;
    if (FOUT) fout[(size_t)n * W + j] = v;
}

// ---------------------------------------------------------------------------
// decode: sigmoid(dot32(z[src], z[dst])); 32 lanes per edge; f32 output
// ---------------------------------------------------------------------------
__global__ __launch_bounds__(256) void w12_decode(
    const int* __restrict__ src, const int* __restrict__ dst,
    const float* __restrict__ z, float* __restrict__ out, int E)
{
    int t = blockIdx.x * 256 + threadIdx.x;
    int e = t >> 5, j = t & 31;
    if (e >= E) return;
    float v = z[(size_t)src[e] * 32 + j] * z[(size_t)dst[e] * 32 + j];
#pragma unroll
    for (int off = 16; off > 0; off >>= 1) v += __shfl_down(v, off, 32);
    if (j == 0) out[e] = 1.f / (1.f + expf(-v));
}

// ---------------------------------------------------------------------------
extern "C" void kernel_launch(void* const* d_in, const int* in_sizes, int n_in,
                              void* d_out, int out_size, void* d_ws, size_t ws_size,
                              hipStream_t stream)
{
    const float* bcat  = (const float*)d_in[0];
    const float* bdesc = (const float*)d_in[1];
    const float* pcat  = (const float*)d_in[2];
    const int*   eib   = (const int*)d_in[3];
    const int*   eip   = (const int*)d_in[4];

    const float *bc_w1=(const float*)d_in[5],  *bc_b1=(const float*)d_in[6],  *bc_a1=(const float*)d_in[7];
    const float *bc_w2=(const float*)d_in[8],  *bc_b2=(const float*)d_in[9],  *bc_a2=(const float*)d_in[10];
    const float *bd_w1=(const float*)d_in[11], *bd_b1=(const float*)d_in[12], *bd_a1=(const float*)d_in[13];
    const float *bd_w2=(const float*)d_in[14], *bd_b2=(const float*)d_in[15], *bd_a2=(const float*)d_in[16];
    const float *bf_w1=(const float*)d_in[17], *bf_b1=(const float*)d_in[18], *bf_a1=(const float*)d_in[19];
    const float *bf_w2=(const float*)d_in[20], *bf_b2=(const float*)d_in[21], *bf_a2=(const float*)d_in[22];
    const float *pc_w1=(const float*)d_in[23], *pc_b1=(const float*)d_in[24], *pc_a1=(const float*)d_in[25];
    const float *pc_w2=(const float*)d_in[26], *pc_b2=(const float*)d_in[27], *pc_a2=(const float*)d_in[28];
    const float *gb_w1=(const float*)d_in[29], *gb_b1=(const float*)d_in[30];
    const float *gb_w2=(const float*)d_in[31], *gb_b2=(const float*)d_in[32];
    const float *gp_w1=(const float*)d_in[33], *gp_b1=(const float*)d_in[34];
    const float *gp_w2=(const float*)d_in[35], *gp_b2=(const float*)d_in[36];

    const int* srcB = eib;  const int* dstB = eib + E_B;
    const int* srcP = eip;  const int* dstP = eip + E_P;

    int*   rowp = (int*)d_ws;               // 200001
    int*   curs = rowp + 200001;            // 200000
    int*   col  = curs + 200000;            // 3200000
    float* dis  = (float*)(col + 3200000);  // 200000
    float* A    = dis + 200000;             // 12800000 f32
    bf16*  Bh   = (bf16*)(A + 12800000);    // 12800000 bf16 (6.4M words)
    float* BhF  = (float*)Bh;
    float* A2   = A + 6400000;

    unsigned short* wz = (unsigned short*)((float*)d_ws + 23000001);
    unsigned short* wz_bc1 = wz;              // 65536
    unsigned short* wz_bc2 = wz_bc1 + 65536;  // 32768
    unsigned short* wz_bf1 = wz_bc2 + 32768;  // 49152
    unsigned short* wz_bf2 = wz_bf1 + 49152;  // 32768
    unsigned short* wz_pc1 = wz_bf2 + 32768;  // 212992
    unsigned short* wz_pc2 = wz_pc1 + 212992; // 32768
    unsigned short* wz_bd1 = wz_pc2 + 32768;  // 2048
    unsigned short* wz_bd2 = wz_bd1 + 2048;   // 2048
    int* bsum = (int*)(wz_bd2 + 2048);        // 1024 ints

    float* out_zb = (float*)d_out;          // [N_B x 32]
    float* out_ab = out_zb + 6400000;       // [E_B]
    float* out_zp = out_ab + 3200000;       // [N_P x 32]
    float* out_ap = out_zp + 3200000;       // [E_P]

    // ---- weight conversion ----
    {
        int t1 = 4  * 32 * 64;  cvt_w<<<(t1 + 255)/256, 256, 0, stream>>>(bc_w1, wz_bc1, 110, 4,  512);
        int t2 = 16 * 4  * 64;  cvt_w<<<(t2 + 255)/256, 256, 0, stream>>>(bc_w2, wz_bc2, 512, 16, 64);
        int t3 = 3  * 32 * 64;  cvt_w<<<(t3 + 255)/256, 256, 0, stream>>>(bf_w1, wz_bf1, 96,  3,  512);
        int t4 = 16 * 4  * 64;  cvt_w<<<(t4 + 255)/256, 256, 0, stream>>>(bf_w2, wz_bf2, 512, 16, 64);
        int t5 = 13 * 32 * 64;  cvt_w<<<(t5 + 255)/256, 256, 0, stream>>>(pc_w1, wz_pc1, 401, 13, 512);
        int t6 = 16 * 4  * 64;  cvt_w<<<(t6 + 255)/256, 256, 0, stream>>>(pc_w2, wz_pc2, 512, 16, 64);
        int t7 = 1  * 4  * 64;  cvt_w<<<(t7 + 255)/256, 256, 0, stream>>>(bd_w1, wz_bd1, 13,  1,  64);
        int t8 = 2  * 2  * 64;  cvt_w<<<(t8 + 255)/256, 256, 0, stream>>>(bd_w2, wz_bd2, 64,  2,  32);
    }

    const int nsb_B = (N_B + 1 + SCAN_CHUNK - 1) / SCAN_CHUNK;   // 98
    const int nsb_P = (N_P + 1 + SCAN_CHUNK - 1) / SCAN_CHUNK;   // 49

    // ================= buildings: CSR =======================================
    w12_zero_int<<<(N_B + 1 + 255) / 256, 256, 0, stream>>>(rowp, N_B + 1);
    w12_hist    <<<(E_B + 255) / 256, 256, 0, stream>>>(dstB, rowp, E_B);
    scan_p1     <<<nsb_B, 256, 0, stream>>>(rowp, N_B + 1, bsum);
    w12_scan    <<<1, 256, 0, stream>>>(bsum, nsb_B);
    scan_p3     <<<nsb_B, 256, 0, stream>>>(rowp, N_B + 1, bsum);
    w12_copy_int<<<(N_B + 255) / 256, 256, 0, stream>>>(rowp, curs, N_B);
    w12_fill    <<<(E_B + 255) / 256, 256, 0, stream>>>(srcB, dstB, curs, col, E_B);
    w12_dis     <<<(N_B + 255) / 256, 256, 0, stream>>>(rowp, dis, N_B);

    // ================= buildings: MLPs (direct-global MFMA) =================
    mlp_g<110,0,128,512,64><<<N_B/32, 256, 0, stream>>>(
        bcat,110, (const float*)nullptr,0,
        wz_bc1, bc_b1, bc_a1, wz_bc2, bc_b2, bc_a2, A);
    mlp_g<13,0,32,64,32><<<N_B/32, 256, 0, stream>>>(
        bdesc,13, (const float*)nullptr,0,
        wz_bd1, bd_b1, bd_a1, wz_bd2, bd_b2, bd_a2, BhF);
    mlp_g<64,32,96,512,64><<<N_B/32, 256, 0, stream>>>(
        A,64, BhF,32,
        wz_bf1, bf_b1, bf_a1, wz_bf2, bf_b2, bf_a2, A);

    // ================= buildings: GCN + decode ==============================
    w12_gemm<64,64><<<(N_B*64 + 255)/256, 256, 0, stream>>>(A, gb_w1, Bh, N_B);
    w12_gcn<64,true,false><<<(N_B*64 + 255)/256, 256, 0, stream>>>(
        rowp, col, dis, Bh, gb_b1, A, (float*)nullptr, N_B);
    w12_gemm<64,32><<<(N_B*32 + 255)/256, 256, 0, stream>>>(A, gb_w2, Bh, N_B);
    w12_gcn<32,false,true><<<(N_B*32 + 255)/256, 256, 0, stream>>>(
        rowp, col, dis, Bh, gb_b2, A, out_zb, N_B);

    w12_decode<<<(E_B*32 + 255)/256, 256, 0, stream>>>(srcB, dstB, A, out_ab, E_B);

    // ================= POIs =================================================
    w12_zero_int<<<(N_P + 1 + 255) / 256, 256, 0, stream>>>(rowp, N_P + 1);
    w12_hist    <<<(E_P + 255) / 256, 256, 0, stream>>>(dstP, rowp, E_P);
    scan_p1     <<<nsb_P, 256, 0, stream>>>(rowp, N_P + 1, bsum);
    w12_scan    <<<1, 256, 0, stream>>>(bsum, nsb_P);
    scan_p3     <<<nsb_P, 256, 0, stream>>>(rowp, N_P + 1, bsum);
    w12_copy_int<<<(N_P + 255) / 256, 256, 0, stream>>>(rowp, curs, N_P);
    w12_fill    <<<(E_P + 255) / 256, 256, 0, stream>>>(srcP, dstP, curs, col, E_P);
    w12_dis     <<<(N_P + 255) / 256, 256, 0, stream>>>(rowp, dis, N_P);

    mlp_g<401,0,416,512,64><<<N_P/32, 256, 0, stream>>>(
        pcat,401, (const float*)nullptr,0,
        wz_pc1, pc_b1, pc_a1, wz_pc2, pc_b2, pc_a2, A2);

    w12_gemm<64,64><<<(N_P*64 + 255)/256, 256, 0, stream>>>(A2, gp_w1, Bh, N_P);
    w12_gcn<64,true,false><<<(N_P*64 + 255)/256, 256, 0, stream>>>(
        rowp, col, dis, Bh, gp_b1, A2, (float*)nullptr, N_P);
    w12_gemm<64,32><<<(N_P*32 + 255)/256, 256, 0, stream>>>(A2, gp_w2, Bh, N_P);
    w12_gcn<32,false,true><<<(N_P*32 + 255)/256, 256, 0, stream>>>(
        rowp, col, dis, Bh, gp_b2, A2, out_zp, N_P);

    w12_decode<<<(E_P*32 + 255)/256, 256, 0, stream>>>(srcP, dstP, A2, out_ap, E_P);
}